// Round 1
// baseline (111.927 us; speedup 1.0000x reference)
//
#include <hip/hip_runtime.h>
#include <cmath>

#define HH  64
#define WW  96
#define CC  128
#define BB  2
#define HWH (HH*WW)

// Block: 640 threads = h(2 channel halves) x j(10 patch rows) x pix(32 consecutive x)
// Grid: (W/32=3, H=64, B=2) = 384 blocks
__global__ __launch_bounds__(640) void corr_kernel(
    const float* __restrict__ I1,
    const float* __restrict__ I2,
    const float* __restrict__ flow,
    float* __restrict__ out)
{
    // D-grid accumulators: [half][j][pixel][16-col window(+1 pad)]
    __shared__ float Acc[2][10][32][17];

    const int tid = threadIdx.x;
    const int pix = tid & 31;
    const int h   = tid / 320;        // channel half (wave-uniform: 320 = 5 waves)
    const int j   = (tid >> 5) % 10;  // patch grid row 0..9

    const int x = blockIdx.x * 32 + pix;
    const int y = blockIdx.y;
    const int b = blockIdx.z;

    const float cx = (float)x + flow[((b*2+0)*HH + y)*WW + x];
    const float cy = (float)y + flow[((b*2+1)*HH + y)*WW + x];
    const int x0c = (int)floorf(cx);
    const int y0c = (int)floorf(cy);

    // 16-dword aligned column window [s, s+15] covering all valid cols x0c-4..x0c+5
    int s = (x0c - 4) & ~3;           // two's-complement & floors toward -inf multiples of 4
    s = min(max(s, 0), WW - 16);
    const int o_off = (x0c - 4) - s;  // window offset of grid col i=0 (may be <0 at edges)

    const int iy  = y0c - 4 + j;
    const int iyc = min(max(iy, 0), HH - 1);  // clamped row for safe addressing; masked later

    float acc[16];
#pragma unroll
    for (int w = 0; w < 16; ++w) acc[w] = 0.f;

    const float* p1 = I1 + (size_t)(b*CC + h*64) * HWH + (y*WW + x);
    const float* p2 = I2 + (size_t)(b*CC + h*64) * HWH + (iyc*WW + s); // 16B aligned (W,s mult of 4)

#pragma unroll 2
    for (int c = 0; c < 64; ++c) {
        const float a = p1[(size_t)c * HWH];
        const float4 q0 = *(const float4*)(p2 + (size_t)c*HWH);
        const float4 q1 = *(const float4*)(p2 + (size_t)c*HWH + 4);
        const float4 q2 = *(const float4*)(p2 + (size_t)c*HWH + 8);
        const float4 q3 = *(const float4*)(p2 + (size_t)c*HWH + 12);
        acc[0]  += a * q0.x;  acc[1]  += a * q0.y;
        acc[2]  += a * q0.z;  acc[3]  += a * q0.w;
        acc[4]  += a * q1.x;  acc[5]  += a * q1.y;
        acc[6]  += a * q1.z;  acc[7]  += a * q1.w;
        acc[8]  += a * q2.x;  acc[9]  += a * q2.y;
        acc[10] += a * q2.z;  acc[11] += a * q2.w;
        acc[12] += a * q3.x;  acc[13] += a * q3.y;
        acc[14] += a * q3.z;  acc[15] += a * q3.w;
    }

#pragma unroll
    for (int w = 0; w < 16; ++w) Acc[h][j][pix][w] = acc[w];  // stride 17: conflict-free

    __syncthreads();

    // ---- combine phase: same pixel identity, new role over outputs ----
    const float wx1 = cx - (float)x0c;
    const float wx0 = 1.f - wx1;
    const float wy1 = cy - (float)y0c;
    const float wy0 = 1.f - wy1;

    float* outb = out + (size_t)b * 81 * HWH + (y*WW + x);
    const int q = tid >> 5;  // 0..19

#pragma unroll
    for (int k = 0; k < 5; ++k) {
        const int o = q + 20*k;
        if (o < 81) {
            const int dyi = o / 9;
            const int dxi = o - dyi*9;
            const int ix0 = x0c - 4 + dxi;
            const int iy0 = y0c - 4 + dyi;
            const bool vx0 = (ix0   >= 0) && (ix0   < WW);
            const bool vx1 = (ix0+1 >= 0) && (ix0+1 < WW);
            const bool vy0 = (iy0   >= 0) && (iy0   < HH);
            const bool vy1 = (iy0+1 >= 0) && (iy0+1 < HH);
            // valid cols are provably inside [0,15]; clamp only protects masked-out reads
            const int i0 = min(max(o_off + dxi,     0), 15);
            const int i1 = min(max(o_off + dxi + 1, 0), 15);
            const float d00 = Acc[0][dyi  ][pix][i0] + Acc[1][dyi  ][pix][i0];
            const float d01 = Acc[0][dyi  ][pix][i1] + Acc[1][dyi  ][pix][i1];
            const float d10 = Acc[0][dyi+1][pix][i0] + Acc[1][dyi+1][pix][i0];
            const float d11 = Acc[0][dyi+1][pix][i1] + Acc[1][dyi+1][pix][i1];
            const float r0 = (vx0 ? wx0*d00 : 0.f) + (vx1 ? wx1*d01 : 0.f);
            const float r1 = (vx0 ? wx0*d10 : 0.f) + (vx1 ? wx1*d11 : 0.f);
            const float v  = (vy0 ? wy0*r0 : 0.f) + (vy1 ? wy1*r1 : 0.f);
            outb[(size_t)o * HWH] = v;
        }
    }
}

extern "C" void kernel_launch(void* const* d_in, const int* in_sizes, int n_in,
                              void* d_out, int out_size, void* d_ws, size_t ws_size,
                              hipStream_t stream)
{
    const float* I1   = (const float*)d_in[0];
    const float* I2   = (const float*)d_in[1];
    const float* flow = (const float*)d_in[2];
    float* out = (float*)d_out;

    dim3 grid(WW/32, HH, BB);
    corr_kernel<<<grid, dim3(640), 0, stream>>>(I1, I2, flow, out);
}